// Round 11
// baseline (2618.290 us; speedup 1.0000x reference)
//
#include <hip/hip_runtime.h>
#include <hip/hip_fp16.h>

// Wavefront-pipelined 20-layer ReLU RNN for MI355X — round 11.
// r10 post-mortem: LDS-throughput-bound (~2.6k of ~3.0k cy/step), mostly
// REDUNDANT A-frag reads (all 8 waves read the same X- and h-tiles).
// Fix: WAVE SPECIALIZATION.
//  - H-waves (0-3): serial h-GEMM only (wave owns 64 cols; 4 waves = N=256).
//    LDS A-read traffic halves vs r10; weights wf[8][4]=128 VGPR.
//  - X-waves (4-7): XP = X*W_ih^T + biases, reading A-frags DIRECTLY from the
//    upstream ring with relaxed agent-scope u64 loads (MALL-coherent; vmem
//    pipe was idle). bufX + prefetch/unscramble machinery deleted.
//    2-step pipeline: at step t issue loads X(t+2), MFMA X(t+1) -> XP,
//    export h(t-1), amortized polls (every 4 steps).
//  - XP exchange via LDS xpB[2][256][4] u64 (C-layout packed: 4 rows/entry):
//    1 ds_write_b64 + 1 ds_read_b64 per lane per nt.
//  - Counters step-granular; publishes after the top barrier (vmcnt drained
//    by __syncthreads) -> drain-free and race-free as in r7-r10.

#define T_    784
#define H_    256
#define L_    20
#define C_    10
#define G_    8
#define BM_   16
#define SW_   280    // lH row stride (halves)
#define FQW_  1024   // u64 words per ring frame (16x256 halves = 8KB)
#define TPB_  512

typedef _Float16 v8h __attribute__((ext_vector_type(8)));
typedef float    v4f __attribute__((ext_vector_type(4)));
typedef unsigned long long u64;

union U64H { u64 u; _Float16 h[4]; };
union U2H  { u64 u[2]; v8h v; };

__device__ __forceinline__ u64 rload(const u64* p) {
    return __hip_atomic_load(p, __ATOMIC_RELAXED, __HIP_MEMORY_SCOPE_AGENT);
}
__device__ __forceinline__ void rstore(u64* p, u64 v) {
    __hip_atomic_store(p, v, __ATOMIC_RELAXED, __HIP_MEMORY_SCOPE_AGENT);
}
__device__ __forceinline__ unsigned rload32(unsigned* p) {
    return __hip_atomic_load(p, __ATOMIC_RELAXED, __HIP_MEMORY_SCOPE_AGENT);
}
__device__ __forceinline__ void rstore32(unsigned* p, unsigned v) {
    __hip_atomic_store(p, v, __ATOMIC_RELAXED, __HIP_MEMORY_SCOPE_AGENT);
}

__global__ __launch_bounds__(TPB_, 2)
void rnn_wavefront(const float* __restrict__ x,
                   const float* __restrict__ W_ih0,
                   const float* __restrict__ b_ih0,
                   const float* __restrict__ W_ih,
                   const float* __restrict__ b_ih,
                   const float* __restrict__ W_hh,
                   const float* __restrict__ b_hh,
                   const float* __restrict__ W_fc,
                   const float* __restrict__ b_fc,
                   float* __restrict__ out,
                   unsigned* __restrict__ prod,   // [L_][G_] steps exported+drained
                   unsigned* __restrict__ cons,   // [L_][G_] frames read-complete
                   u64* __restrict__ ring,        // [L_][G_][F][FQW_]
                   int fmask)                     // F-1, F power of two
{
    const int l    = blockIdx.x >> 3;
    const int g    = blockIdx.x & 7;
    const int tid  = threadIdx.x;
    const int lane = tid & 63;
    const int wave = tid >> 6;          // 0..7
    const int quad = lane >> 4;
    const int s16  = lane & 15;
    const int nb   = (wave & 3) * 64;   // column block owned (by role group)
    const bool isH = wave < 4;
    const int F    = fmask + 1;

    __shared__ __align__(16) _Float16 lH[2][BM_][SW_];  // h ping-pong
    __shared__ u64 xpB[2][H_][4];                       // XP exchange, [par][n][q]
    __shared__ _Float16 xT[BM_][T_];                    // layer-0 x tile

    for (int i = tid; i < 2 * BM_ * SW_; i += TPB_) (&lH[0][0][0])[i] = (_Float16)0.f;
    if (l == 0)
        for (int i = tid; i < BM_ * T_; i += TPB_)
            (&xT[0][0])[i] = (_Float16)x[(size_t)(g * BM_) * T_ + i];

    // ---- weights: H-waves = W_hh[l]; X-waves = W_ih[l-1] (l>0) ----
    v8h wf[8][4];
#pragma unroll
    for (int kt = 0; kt < 8; ++kt) {
#pragma unroll
        for (int nt = 0; nt < 4; ++nt) {
            const int j = nb + nt * 16 + s16;
            v8h w;
            const float* src = nullptr;
            if (isH)         src = &W_hh[((size_t)l * H_ + j) * H_ + kt * 32 + quad * 8];
            else if (l > 0)  src = &W_ih[((size_t)(l - 1) * H_ + j) * H_ + kt * 32 + quad * 8];
            if (src) {
#pragma unroll
                for (int i = 0; i < 8; ++i) w[i] = (_Float16)src[i];
            } else {
#pragma unroll
                for (int i = 0; i < 8; ++i) w[i] = (_Float16)0.f;
            }
            wf[kt][nt] = w;
        }
    }
    float bias[4], w0v[4];
    if (!isH) {
#pragma unroll
        for (int nt = 0; nt < 4; ++nt) {
            const int j = nb + nt * 16 + s16;
            bias[nt] = b_hh[l * H_ + j] + ((l == 0) ? b_ih0[j] : b_ih[(l - 1) * H_ + j]);
            w0v[nt]  = (l == 0) ? W_ih0[j] : 0.f;
        }
    }

    unsigned* upprod = prod + ((l > 0 ? l - 1 : 0) * G_ + g);
    unsigned* myprod = prod + (l * G_ + g);
    unsigned* mycons = cons + (l * G_ + g);
    unsigned* dncons = cons + (((l < L_ - 1) ? l + 1 : l) * G_ + g);
    u64* myring = ring + (size_t)(l * G_ + g) * (size_t)F * FQW_;
    u64* upring = ring + (size_t)((l > 0 ? l - 1 : 0) * G_ + g) * (size_t)F * FQW_;

    unsigned pSeen = 0, cSeen = 0;   // tid256 / tid320 private
    u64 fr[2][16];                   // X-wave A-frag pipeline (X(t+1) in fr[t&1])
    const int aidx = s16 * 64 + quad * 2;   // u64 index of this lane's frag base

    // ---- prologue ----
    if (l > 0) {
        if (tid == 256) {   // covers loads at step 0 (X(2)) and prologue loads
            while (pSeen < 3u) {
                pSeen = rload32(upprod);
                if (pSeen < 3u) __builtin_amdgcn_s_sleep(2);
            }
        }
        __syncthreads();
        if (!isH) {
            u64 t0[16];
#pragma unroll
            for (int kt = 0; kt < 8; ++kt) {
                t0[2 * kt]     = rload(upring + aidx + kt * 8);
                t0[2 * kt + 1] = rload(upring + aidx + kt * 8 + 1);
                fr[0][2 * kt]     = rload(upring + FQW_ + aidx + kt * 8);
                fr[0][2 * kt + 1] = rload(upring + FQW_ + aidx + kt * 8 + 1);
            }
            v4f a[4];
#pragma unroll
            for (int nt = 0; nt < 4; ++nt) a[nt] = (v4f){bias[nt], bias[nt], bias[nt], bias[nt]};
#pragma unroll
            for (int kt = 0; kt < 8; ++kt) {
                U2H f; f.u[0] = t0[2 * kt]; f.u[1] = t0[2 * kt + 1];
#pragma unroll
                for (int nt = 0; nt < 4; ++nt)
                    a[nt] = __builtin_amdgcn_mfma_f32_16x16x32_f16(f.v, wf[kt][nt], a[nt], 0, 0, 0);
            }
#pragma unroll
            for (int nt = 0; nt < 4; ++nt) {
                U64H p;
#pragma unroll
                for (int r = 0; r < 4; ++r) p.h[r] = (_Float16)a[nt][r];
                xpB[0][nb + nt * 16 + s16][quad] = p.u;
            }
        }
    } else {
        __syncthreads();   // xT visible
        if (!isH) {
            float xv[4];
#pragma unroll
            for (int r = 0; r < 4; ++r) xv[r] = (float)xT[quad * 4 + r][0];
#pragma unroll
            for (int nt = 0; nt < 4; ++nt) {
                U64H p;
#pragma unroll
                for (int r = 0; r < 4; ++r) p.h[r] = (_Float16)(bias[nt] + xv[r] * w0v[nt]);
                xpB[0][nb + nt * 16 + s16][quad] = p.u;
            }
        }
    }

#pragma unroll 2
    for (int t = 0; t < T_; ++t) {
        __syncthreads();   // drains vmcnt in every wave (HIP __syncthreads semantics)

        if (isH) {
            if (tid == 0) {   // fire-and-forget, drain carried by the barrier
                if (l < L_ - 1 && t >= 2) rstore32(myprod, (unsigned)(t - 1));
                if (l > 0)               rstore32(mycons, (unsigned)(t + 2));
            }
            // ---- serial h-GEMM: 32 MFMA, 8 b128 reads ----
            v4f acc[4];
#pragma unroll
            for (int nt = 0; nt < 4; ++nt) acc[nt] = (v4f){0.f, 0.f, 0.f, 0.f};
#pragma unroll
            for (int kt = 0; kt < 8; ++kt) {
                v8h a = *(const v8h*)&lH[t & 1][s16][kt * 32 + quad * 8];
#pragma unroll
                for (int nt = 0; nt < 4; ++nt)
                    acc[nt] = __builtin_amdgcn_mfma_f32_16x16x32_f16(a, wf[kt][nt], acc[nt], 0, 0, 0);
            }
            // ---- epilogue: relu(acc + XP(t)) -> lH[(t+1)&1] ----
#pragma unroll
            for (int nt = 0; nt < 4; ++nt) {
                const int n = nb + nt * 16 + s16;
                U64H xp; xp.u = xpB[t & 1][n][quad];
#pragma unroll
                for (int r = 0; r < 4; ++r) {
                    float v = acc[nt][r] + (float)xp.h[r];
                    v = fmaxf(v, 0.f);
                    lH[(t + 1) & 1][quad * 4 + r][n] = (_Float16)v;
                }
            }
        } else {
            // ---- amortized polls (every 4 steps, in X-wave slack) ----
            if (tid == 256 && l > 0 && (t & 3) == 0 && t <= T_ - 4) {
                const unsigned tgt = (unsigned)((t + 7 < T_) ? t + 7 : T_);
                while (pSeen < tgt) {
                    pSeen = rload32(upprod);
                    if (pSeen < tgt) __builtin_amdgcn_s_sleep(2);
                }
            }
            if (tid == 320 && l < L_ - 1 && (t & 3) == 0 && t + 5 > F) {
                const unsigned tgt = (unsigned)(t + 5 - F);
                while (cSeen < tgt) {
                    cSeen = rload32(dncons);
                    if (cSeen < tgt) __builtin_amdgcn_s_sleep(2);
                }
            }
            // ---- issue loads: X(t+2) A-frags straight from upstream ring ----
            if (l > 0 && t + 2 <= T_ - 1) {
                const u64* base = upring + (size_t)((t + 2) & fmask) * FQW_ + aidx;
#pragma unroll
                for (int kt = 0; kt < 8; ++kt) {
                    fr[(t + 1) & 1][2 * kt]     = rload(base + kt * 8);
                    fr[(t + 1) & 1][2 * kt + 1] = rload(base + kt * 8 + 1);
                }
            }
            // ---- XP(t+1): 32 MFMA on frags loaded last step ----
            if (t + 1 <= T_ - 1) {
                if (l > 0) {
                    v4f a[4];
#pragma unroll
                    for (int nt = 0; nt < 4; ++nt) a[nt] = (v4f){bias[nt], bias[nt], bias[nt], bias[nt]};
#pragma unroll
                    for (int kt = 0; kt < 8; ++kt) {
                        U2H f; f.u[0] = fr[t & 1][2 * kt]; f.u[1] = fr[t & 1][2 * kt + 1];
#pragma unroll
                        for (int nt = 0; nt < 4; ++nt)
                            a[nt] = __builtin_amdgcn_mfma_f32_16x16x32_f16(f.v, wf[kt][nt], a[nt], 0, 0, 0);
                    }
#pragma unroll
                    for (int nt = 0; nt < 4; ++nt) {
                        U64H p;
#pragma unroll
                        for (int r = 0; r < 4; ++r) p.h[r] = (_Float16)a[nt][r];
                        xpB[(t + 1) & 1][nb + nt * 16 + s16][quad] = p.u;
                    }
                } else {
                    float xv[4];
#pragma unroll
                    for (int r = 0; r < 4; ++r) xv[r] = (float)xT[quad * 4 + r][t + 1];
#pragma unroll
                    for (int nt = 0; nt < 4; ++nt) {
                        U64H p;
#pragma unroll
                        for (int r = 0; r < 4; ++r) p.h[r] = (_Float16)(bias[nt] + xv[r] * w0v[nt]);
                        xpB[(t + 1) & 1][nb + nt * 16 + s16][quad] = p.u;
                    }
                }
            }
            // ---- export h(t-1) from lH[t&1] -> own ring frame ----
            if (l < L_ - 1 && t >= 1) {
                const int te = tid & 255, me = te >> 4, ch = te & 15;
                U2H r0, r1;
                r0.v = *(const v8h*)&lH[t & 1][me][ch * 16];
                r1.v = *(const v8h*)&lH[t & 1][me][ch * 16 + 8];
                u64* d = myring + (size_t)((t - 1) & fmask) * FQW_ + me * 64 + ch * 4;
                rstore(d,     r0.u[0]);
                rstore(d + 1, r0.u[1]);
                rstore(d + 2, r1.u[0]);
                rstore(d + 3, r1.u[1]);
            }
        }
    }

    // ---- tail ----
    __syncthreads();
    if (l < L_ - 1) {
        if (!isH) {   // export h(T-1) (in lH[0])
            const int te = tid & 255, me = te >> 4, ch = te & 15;
            U2H r0, r1;
            r0.v = *(const v8h*)&lH[0][me][ch * 16];
            r1.v = *(const v8h*)&lH[0][me][ch * 16 + 8];
            u64* d = myring + (size_t)((T_ - 1) & fmask) * FQW_ + me * 64 + ch * 4;
            rstore(d,     r0.u[0]);
            rstore(d + 1, r0.u[1]);
            rstore(d + 2, r1.u[0]);
            rstore(d + 3, r1.u[1]);
        }
        __syncthreads();   // drain tail exports
        if (tid == 0) rstore32(myprod, (unsigned)T_);
    } else {
        if (tid < BM_ * C_) {
            const int bl = tid / C_;
            const int c  = tid % C_;
            float sum = b_fc[c];
            for (int k = 0; k < H_; ++k) sum += (float)lH[0][bl][k] * W_fc[c * H_ + k];
            out[(size_t)(g * BM_ + bl) * C_ + c] = sum;
        }
    }
}

extern "C" void kernel_launch(void* const* d_in, const int* in_sizes, int n_in,
                              void* d_out, int out_size, void* d_ws, size_t ws_size,
                              hipStream_t stream) {
    const float* x     = (const float*)d_in[0];
    const float* W_ih0 = (const float*)d_in[1];
    const float* b_ih0 = (const float*)d_in[2];
    const float* W_ih  = (const float*)d_in[3];
    const float* b_ih  = (const float*)d_in[4];
    const float* W_hh  = (const float*)d_in[5];
    const float* b_hh  = (const float*)d_in[6];
    const float* W_fc  = (const float*)d_in[7];
    const float* b_fc  = (const float*)d_in[8];
    float* out = (float*)d_out;

    const size_t cntBytes = (size_t)L_ * G_ * sizeof(unsigned);
    unsigned* prod = (unsigned*)d_ws;
    unsigned* cons = (unsigned*)((char*)d_ws + cntBytes);
    u64* ring      = (u64*)((char*)d_ws + 2 * cntBytes);

    // frames per link (8KB each), by workspace: 64 -> 80MB, 32 -> 40MB, 16 -> 20MB
    const size_t frameBytes = (size_t)FQW_ * 8;
    const size_t base = 2 * cntBytes;
    int F = 16;
    if (ws_size >= base + (size_t)L_ * G_ * 64 * frameBytes) F = 64;
    else if (ws_size >= base + (size_t)L_ * G_ * 32 * frameBytes) F = 32;

    hipMemsetAsync(d_ws, 0, 2 * cntBytes, stream);

    rnn_wavefront<<<dim3(L_ * G_), dim3(TPB_), 0, stream>>>(
        x, W_ih0, b_ih0, W_ih, b_ih, W_hh, b_hh, W_fc, b_fc,
        out, prod, cons, ring, F - 1);
}

// Round 12
// 1118.014 us; speedup vs baseline: 2.3419x; 2.3419x over previous
//
#include <hip/hip_runtime.h>
#include <hip/hip_fp16.h>

// Wavefront-pipelined 20-layer ReLU RNN for MI355X — round 12.
// Base = round 9 (best: 1122us) with the GEMM TRANSPOSED: h^T = W·h^T.
// f16 MFMA A/B fragment layouts are symmetric (lane&15 x 8 contiguous k), so
// the transpose is just swapping the mfma operand order: wf (loaded B[k][n])
// serves as A[m=n][k]; the lH row-read serves as B[k][m]. C/D then holds
// D[n = quad*4+r][m = s16] per lane -> epilogue writes 4 CONSECUTIVE columns
// of row s16 = one ds_write_b64 (was 8 scattered ds_write_b16). lH layout,
// ring format, export, bufX staging, XP-burst structure unchanged from r9.
// r11's wave-specialization (4x redundant ring reads -> 4.45GB HBM) reverted.

#define B_    128
#define T_    784
#define H_    256
#define L_    20
#define C_    10
#define G_    8      // batch slices
#define BM_   16     // batch rows per block
#define S_    4      // timesteps per superstep / ring slot
#define NS_   196    // T_/S_
#define SW_   280    // LDS row stride in halves (140 dwords = 12 mod 32)
#define RQWS_ 4096   // u64 words per ring slot (4 x 16 x 256 halves = 32KB)
#define TPB_  512

typedef _Float16 v8h __attribute__((ext_vector_type(8)));
typedef _Float16 v4h __attribute__((ext_vector_type(4)));
typedef float    v4f __attribute__((ext_vector_type(4)));
typedef unsigned long long u64;

union U64H { u64 u; _Float16 h[4]; };

__global__ __launch_bounds__(TPB_, 2)
void rnn_wavefront(const float* __restrict__ x,
                   const float* __restrict__ W_ih0,
                   const float* __restrict__ b_ih0,
                   const float* __restrict__ W_ih,
                   const float* __restrict__ b_ih,
                   const float* __restrict__ W_hh,
                   const float* __restrict__ b_hh,
                   const float* __restrict__ W_fc,
                   const float* __restrict__ b_fc,
                   float* __restrict__ out,
                   unsigned* __restrict__ prod,    // [L_][G_] supersteps complete
                   unsigned* __restrict__ cons,    // [L_][G_] supersteps consumed
                   u64* __restrict__ ring,         // [L_][G_][R][RQWS_]
                   int rmask)                      // R-1, R power of two
{
    const int l    = blockIdx.x >> 3;
    const int g    = blockIdx.x & 7;
    const int tid  = threadIdx.x;
    const int lane = tid & 63;
    const int wave = tid >> 6;          // 0..7
    const int quad = lane >> 4;
    const int s16  = lane & 15;
    const int nbase = wave * 32;        // each wave owns 32 output columns
    const int m_e  = tid >> 5;          // export/pf row (0..15)
    const int n_e  = (tid & 31) * 8;    // export/pf col base (0..248)

    __shared__ __align__(16) _Float16 bufX[S_][BM_][SW_];  // staged input slot
    __shared__ __align__(16) _Float16 lH[2][BM_][SW_];     // own h, ping-pong

    for (int i = tid; i < 2 * BM_ * SW_; i += TPB_) (&lH[0][0][0])[i] = (_Float16)0.f;

    // ---- weight fragments: lane holds W[n = nbase+nt*16+s16][k = kt*32+quad*8 ..]
    // (loaded exactly as r9's B-frags; used as the A operand of the
    //  transposed GEMM, where A[m][k] with m = n-row.)
    v8h wf[16][2];
#pragma unroll
    for (int kt = 0; kt < 16; ++kt) {
        const int k0 = kt * 32 + quad * 8;
#pragma unroll
        for (int nt = 0; nt < 2; ++nt) {
            const int j = nbase + nt * 16 + s16;
            v8h w;
            if (kt < 8) {
                if (l == 0) {
#pragma unroll
                    for (int i = 0; i < 8; ++i) w[i] = (_Float16)0.f;
                } else {
                    const float* src = &W_ih[(((size_t)(l - 1) * H_) + j) * H_ + k0];
#pragma unroll
                    for (int i = 0; i < 8; ++i) w[i] = (_Float16)src[i];
                }
            } else {
                const float* src = &W_hh[(((size_t)l * H_) + j) * H_ + (k0 - 256)];
#pragma unroll
                for (int i = 0; i < 8; ++i) w[i] = (_Float16)src[i];
            }
            wf[kt][nt] = w;
        }
    }

    // bias/w0 indexed by the transposed C/D layout: lane owns rows
    // n = nbase + nt*16 + quad*4 + r  (r = 0..3), col m = s16.
    float bias[2][4], w0v[2][4];
#pragma unroll
    for (int nt = 0; nt < 2; ++nt)
#pragma unroll
        for (int r = 0; r < 4; ++r) {
            const int j = nbase + nt * 16 + quad * 4 + r;
            bias[nt][r] = b_hh[l * H_ + j] + ((l == 0) ? b_ih0[j] : b_ih[(l - 1) * H_ + j]);
            w0v[nt][r]  = (l == 0) ? W_ih0[j] : 0.f;
        }

    unsigned* upprod = prod + ((l > 0 ? l - 1 : 0) * G_ + g);
    unsigned* myprod = prod + (l * G_ + g);
    unsigned* mycons = cons + (l * G_ + g);
    unsigned* dncons = cons + (((l < L_ - 1) ? l + 1 : l) * G_ + g);
    const unsigned R = (unsigned)rmask + 1u;
    u64* myring = ring + ((size_t)(l * G_ + g) * (size_t)R) * RQWS_;
    u64* upring = ring + ((size_t)((l > 0 ? l - 1 : 0) * G_ + g) * (size_t)R) * RQWS_;

    unsigned pSeen = 0, cSeen = 0;         // tid64 / tid128 private
    const size_t eidx = (size_t)m_e * 64 + (size_t)(tid & 31) * 2;  // u64 idx in slot

    // ---- prologue (l>0): wait prod>=2, stage slot 0 into bufX (row-major) ----
    if (l > 0) {
        if (tid == 64) {
            while (pSeen < 2u) {
                pSeen = __hip_atomic_load(upprod, __ATOMIC_RELAXED,
                                          __HIP_MEMORY_SCOPE_AGENT);
                if (pSeen < 2u) __builtin_amdgcn_s_sleep(2);
            }
        }
        __syncthreads();
#pragma unroll
        for (int jj = 0; jj < S_; ++jj) {
            u64 v0 = __hip_atomic_load(upring + (size_t)jj * 1024 + eidx,
                                       __ATOMIC_RELAXED, __HIP_MEMORY_SCOPE_AGENT);
            u64 v1 = __hip_atomic_load(upring + (size_t)jj * 1024 + eidx + 1,
                                       __ATOMIC_RELAXED, __HIP_MEMORY_SCOPE_AGENT);
            *(u64*)&bufX[jj][m_e][n_e]     = v0;
            *(u64*)&bufX[jj][m_e][n_e + 4] = v1;
        }
    }

    for (int s = 0; s < NS_; ++s) {
        const bool pfOK = (l > 0) && (s + 1 < NS_);
        u64 pfv[S_][2];
        v4h XPh[S_][2];   // hoisted X-half results + bias, fp16 (transposed layout)

#pragma unroll
        for (int j = 0; j < S_; ++j) {
            const int t = S_ * s + j;
            __syncthreads();   // step barrier (also drains vmem per compiler)

            if (j == 0) {
                if (tid == 0 && l > 0)
                    __hip_atomic_store(mycons, (unsigned)(s + 1), __ATOMIC_RELAXED,
                                       __HIP_MEMORY_SCOPE_AGENT); // slot s global free
                if (tid == 64 && pfOK) {            // guards pf of slot s+1 at j1
                    const unsigned tgt = (unsigned)(s + 2);
                    while (pSeen < tgt) {
                        pSeen = __hip_atomic_load(upprod, __ATOMIC_RELAXED,
                                                  __HIP_MEMORY_SCOPE_AGENT);
                        if (pSeen < tgt) __builtin_amdgcn_s_sleep(2);
                    }
                }
                if (tid == 128 && l < L_ - 1 && s >= (int)R) {  // guards exports into slot s
                    const unsigned tgt = (unsigned)(s - (int)R + 1);
                    while (cSeen < tgt) {
                        cSeen = __hip_atomic_load(dncons, __ATOMIC_RELAXED,
                                                  __HIP_MEMORY_SCOPE_AGENT);
                        if (cSeen < tgt) __builtin_amdgcn_s_sleep(2);
                    }
                }

                // ---- XP burst (transposed): XP[jj] = W_ih · X(4s+jj)^T + bias ----
                if (l > 0) {
                    v4f xpa[S_][2];
#pragma unroll
                    for (int jj = 0; jj < S_; ++jj)
#pragma unroll
                        for (int nt = 0; nt < 2; ++nt)
                            xpa[jj][nt] = (v4f){bias[nt][0], bias[nt][1],
                                                bias[nt][2], bias[nt][3]};
#pragma unroll
                    for (int jj = 0; jj < S_; ++jj) {
#pragma unroll
                        for (int kt = 0; kt < 8; ++kt) {
                            v8h a = *(const v8h*)&bufX[jj][s16][kt * 32 + quad * 8];
                            xpa[jj][0] = __builtin_amdgcn_mfma_f32_16x16x32_f16(wf[kt][0], a, xpa[jj][0], 0, 0, 0);
                            xpa[jj][1] = __builtin_amdgcn_mfma_f32_16x16x32_f16(wf[kt][1], a, xpa[jj][1], 0, 0, 0);
                        }
                    }
#pragma unroll
                    for (int jj = 0; jj < S_; ++jj)
#pragma unroll
                        for (int nt = 0; nt < 2; ++nt)
#pragma unroll
                            for (int r = 0; r < 4; ++r)
                                XPh[jj][nt][r] = (_Float16)xpa[jj][nt][r];
                } else {
                    // layer 0: XP[n][m] = bias[n] + x[m]*w0[n]; lane col m = s16
#pragma unroll
                    for (int jj = 0; jj < S_; ++jj) {
                        const float xv = x[(size_t)(g * BM_ + s16) * T_ + (S_ * s + jj)];
#pragma unroll
                        for (int nt = 0; nt < 2; ++nt)
#pragma unroll
                            for (int r = 0; r < 4; ++r)
                                XPh[jj][nt][r] = (_Float16)(bias[nt][r] + xv * w0v[nt][r]);
                    }
                }
            }

            if (j == 1) {
                if (tid == 0 && l < L_ - 1 && s >= 1)
                    __hip_atomic_store(myprod, (unsigned)s, __ATOMIC_RELAXED,
                                       __HIP_MEMORY_SCOPE_AGENT); // slots 0..s-1 done
                if (pfOK) {   // prefetch slot s+1 -> regs (used at j3)
                    const u64* base = upring + (size_t)((s + 1) & rmask) * RQWS_;
#pragma unroll
                    for (int jj = 0; jj < S_; ++jj) {
                        pfv[jj][0] = __hip_atomic_load(base + (size_t)jj * 1024 + eidx,
                                                       __ATOMIC_RELAXED,
                                                       __HIP_MEMORY_SCOPE_AGENT);
                        pfv[jj][1] = __hip_atomic_load(base + (size_t)jj * 1024 + eidx + 1,
                                                       __ATOMIC_RELAXED,
                                                       __HIP_MEMORY_SCOPE_AGENT);
                    }
                }
            }

            // ---- export h(t-1) (lag 1 step; lH[t&1] holds h(t-1)) ----
            if (l < L_ - 1 && t > 0) {
                u64 e0 = *(const u64*)&lH[t & 1][m_e][n_e];
                u64 e1 = *(const u64*)&lH[t & 1][m_e][n_e + 4];
                u64* d = myring + (size_t)(((t - 1) >> 2) & rmask) * RQWS_
                                + (size_t)((t - 1) & 3) * 1024 + eidx;
                __hip_atomic_store(d,     e0, __ATOMIC_RELAXED, __HIP_MEMORY_SCOPE_AGENT);
                __hip_atomic_store(d + 1, e1, __ATOMIC_RELAXED, __HIP_MEMORY_SCOPE_AGENT);
            }

            // ---- serial h-MFMA (transposed): D = W_hh · h(t-1)^T, 16 MFMA ----
            v4f acc0 = (v4f){0.f, 0.f, 0.f, 0.f};
            v4f acc1 = (v4f){0.f, 0.f, 0.f, 0.f};
#pragma unroll
            for (int kt = 8; kt < 16; ++kt) {
                v8h a = *(const v8h*)&lH[t & 1][s16][(kt - 8) * 32 + quad * 8];
                acc0 = __builtin_amdgcn_mfma_f32_16x16x32_f16(wf[kt][0], a, acc0, 0, 0, 0);
                acc1 = __builtin_amdgcn_mfma_f32_16x16x32_f16(wf[kt][1], a, acc1, 0, 0, 0);
            }

            // ---- epilogue: relu(XP + acc) -> lH[(t+1)&1]; lane holds
            // D[n = nbase+nt*16+quad*4+r][m = s16] -> ONE b64 write per nt ----
#pragma unroll
            for (int nt = 0; nt < 2; ++nt) {
                const v4f av = nt ? acc1 : acc0;
                U64H pk;
#pragma unroll
                for (int r = 0; r < 4; ++r) {
                    float v = (float)XPh[j][nt][r] + av[r];
                    v = fmaxf(v, 0.f);
                    pk.h[r] = (_Float16)v;
                }
                *(u64*)&lH[(t + 1) & 1][s16][nbase + nt * 16 + quad * 4] = pk.u;
            }

            if (j == S_ - 1) {
                __syncthreads();   // all waves done with bufX of this superstep
                if (pfOK) {        // unscramble: pure ds_write_b64, no extraction
#pragma unroll
                    for (int jj = 0; jj < S_; ++jj) {
                        *(u64*)&bufX[jj][m_e][n_e]     = pfv[jj][0];
                        *(u64*)&bufX[jj][m_e][n_e + 4] = pfv[jj][1];
                    }
                }
            }
        }
    }

    if (l < L_ - 1) {
        // tail: export h(T-1) (in lH[0]: (783+1)&1), drain, publish all done
        u64 e0 = *(const u64*)&lH[0][m_e][n_e];
        u64 e1 = *(const u64*)&lH[0][m_e][n_e + 4];
        u64* d = myring + (size_t)(((T_ - 1) >> 2) & rmask) * RQWS_
                        + (size_t)3 * 1024 + eidx;
        __hip_atomic_store(d,     e0, __ATOMIC_RELAXED, __HIP_MEMORY_SCOPE_AGENT);
        __hip_atomic_store(d + 1, e1, __ATOMIC_RELAXED, __HIP_MEMORY_SCOPE_AGENT);
        __syncthreads();   // drains the exports (vmcnt(0) before s_barrier)
        if (tid == 0)
            __hip_atomic_store(myprod, (unsigned)NS_, __ATOMIC_RELAXED,
                               __HIP_MEMORY_SCOPE_AGENT);
    } else {
        __syncthreads();
        // final FC: out[b] = h_T[b] @ W_fc^T + b_fc; h_T in lH[0]
        if (tid < BM_ * C_) {
            const int bl = tid / C_;
            const int c  = tid % C_;
            float sum = b_fc[c];
            for (int k = 0; k < H_; ++k) sum += (float)lH[0][bl][k] * W_fc[c * H_ + k];
            out[(size_t)(g * BM_ + bl) * C_ + c] = sum;
        }
    }
}

extern "C" void kernel_launch(void* const* d_in, const int* in_sizes, int n_in,
                              void* d_out, int out_size, void* d_ws, size_t ws_size,
                              hipStream_t stream) {
    const float* x     = (const float*)d_in[0];
    const float* W_ih0 = (const float*)d_in[1];
    const float* b_ih0 = (const float*)d_in[2];
    const float* W_ih  = (const float*)d_in[3];
    const float* b_ih  = (const float*)d_in[4];
    const float* W_hh  = (const float*)d_in[5];
    const float* b_hh  = (const float*)d_in[6];
    const float* W_fc  = (const float*)d_in[7];
    const float* b_fc  = (const float*)d_in[8];
    float* out = (float*)d_out;

    const size_t cntBytes = (size_t)L_ * G_ * sizeof(unsigned);   // 640 B each
    unsigned* prod = (unsigned*)d_ws;
    unsigned* cons = (unsigned*)((char*)d_ws + cntBytes);
    u64* ring      = (u64*)((char*)d_ws + 2 * cntBytes);

    // ring slots per link, by available workspace (32 KB per slot per link)
    const size_t slotBytes = (size_t)RQWS_ * 8;                   // 32 KB
    const size_t base = 2 * cntBytes;
    int R = 4;                                                    // 21 MB
    if (ws_size >= base + (size_t)L_ * G_ * 16 * slotBytes) R = 16;      // 84 MB
    else if (ws_size >= base + (size_t)L_ * G_ * 8 * slotBytes) R = 8;   // 42 MB

    hipMemsetAsync(d_ws, 0, 2 * cntBytes, stream);

    rnn_wavefront<<<dim3(L_ * G_), dim3(TPB_), 0, stream>>>(
        x, W_ih0, b_ih0, W_ih, b_ih, W_hh, b_hh, W_fc, b_fc,
        out, prod, cons, ring, R - 1);
}